// Round 1
// 398.793 us; speedup vs baseline: 1.1728x; 1.1728x over previous
//
#include <hip/hip_runtime.h>

#define DIM 240
#define NTYPE 10
#define NFEAT 112
#define NSLOT 176      // per-type: 64 sum_x + 64 sum_x2 + 32 vec + 16 tens
#define NRED  1770     // NTYPE*NSLOT + NTYPE counts
#define PSTRIDE 1792   // per-block partial stride in floats (1770 used)
#define RCHUNK 32      // row chunks in reduce1
#define EPSV 1e-5f

// ws layout (floats):
// [0, nblk*PSTRIDE)                          per-block partials
// [P0 = nblk*PSTRIDE, +RCHUNK*PSTRIDE)       chunk partials (reduce1 output)
// [P1 = P0 + RCHUNK*PSTRIDE, +7200)          params: per type t: sub[240], mul[240], bia[240]

__global__ __launch_bounds__(256) void stats_kernel(const float* __restrict__ x,
        const int* __restrict__ type, float* __restrict__ partial, int B, int nblk)
{
    const int tid = threadIdx.x;
    const bool active = tid < DIM;
    const bool isScalar = tid < 64;

    float accA[NTYPE], accB[NTYPE];
#pragma unroll
    for (int t = 0; t < NTYPE; t++) { accA[t] = 0.f; accB[t] = 0.f; }

    // counter contribution: inactive lane 255 adds 1.0 per row into accA[ty]
    const float inactAdd = (tid == 255) ? 1.f : 0.f;

    auto accum = [&](int ty, float v) {
        const float v2 = v * v;
        const float addA = active ? (isScalar ? v : v2) : inactAdd;
#pragma unroll
        for (int t = 0; t < NTYPE; t++) {
            if (t == ty) { accA[t] += addA; accB[t] += v2; }  // ty wave-uniform -> scalar branch
        }
    };

    // 8 rows per block per sweep: 8 independent loads in flight per wave
    const int stride = nblk * 8;
    for (int row0 = blockIdx.x * 8; row0 + 7 < B; row0 += stride) {
        int ty[8];
#pragma unroll
        for (int j = 0; j < 8; j++) ty[j] = type[row0 + j];
        float v[8];
#pragma unroll
        for (int j = 0; j < 8; j++) v[j] = 0.f;
        if (active) {
            const float* p = x + (size_t)row0 * DIM + tid;
#pragma unroll
            for (int j = 0; j < 8; j++) v[j] = p[j * DIM];
        }
#pragma unroll
        for (int j = 0; j < 8; j++) accum(ty[j], v[j]);
    }
    // tail rows (B % 8 != 0) -- handled by block 0 only
    if (blockIdx.x == 0) {
        for (int r = B & ~7; r < B; r++) {
            const int ty0 = type[r];
            float v = active ? x[(size_t)r * DIM + tid] : 0.f;
            accum(ty0, v);
        }
    }

    // block-level reduction into slot layout, then non-atomic partial flush
    __shared__ float sAcc[NRED];   // 1770
    for (int i = tid; i < NRED; i += 256) sAcc[i] = 0.f;
    __syncthreads();

    if (isScalar) {
#pragma unroll
        for (int t = 0; t < NTYPE; t++) {
            sAcc[t * NSLOT + tid] = accA[t];            // exclusive slot: plain store
            sAcc[t * NSLOT + 64 + tid] = accB[t];
        }
    } else if (tid < 160) {
        const int ch = (tid - 64) / 3;
#pragma unroll
        for (int t = 0; t < NTYPE; t++)
            atomicAdd(&sAcc[t * NSLOT + 128 + ch], accA[t]);   // 3-way LDS atomic
    } else if (tid < DIM) {
        const int ch = (tid - 160) / 5;
#pragma unroll
        for (int t = 0; t < NTYPE; t++)
            atomicAdd(&sAcc[t * NSLOT + 160 + ch], accA[t]);   // 5-way LDS atomic
    } else if (tid == 255) {
#pragma unroll
        for (int t = 0; t < NTYPE; t++)
            sAcc[NTYPE * NSLOT + t] = accA[t];          // counts
    }
    __syncthreads();

    float* __restrict__ dst = partial + (size_t)blockIdx.x * PSTRIDE;
    for (int i = tid; i < NRED; i += 256) dst[i] = sAcc[i];
}

// coalesced cross-block reduction: grid = 7 colChunks x RCHUNK rowChunks
__global__ __launch_bounds__(256) void reduce1_kernel(const float* __restrict__ partial,
        float* __restrict__ gpart, int nblk)
{
    const int colChunk = blockIdx.x % 7;
    const int rowChunk = blockIdx.x / 7;
    const int col = colChunk * 256 + threadIdx.x;       // 0..1791
    const int r0 = (rowChunk * nblk) / RCHUNK;
    const int r1 = ((rowChunk + 1) * nblk) / RCHUNK;
    float acc = 0.f;
#pragma unroll 8
    for (int r = r0; r < r1; r++)
        acc += partial[(size_t)r * PSTRIDE + col];
    gpart[rowChunk * PSTRIDE + col] = acc;
}

__global__ __launch_bounds__(256) void finalize_kernel(const float* __restrict__ gpart,
        const float* __restrict__ weight, const float* __restrict__ bias,
        float* __restrict__ params)
{
    const int t = blockIdx.x;
    const int c = threadIdx.x;

    __shared__ float scnt;
    if (c == 0) {
        float cs = 0.f;
#pragma unroll
        for (int k = 0; k < RCHUNK; k++)
            cs += gpart[k * PSTRIDE + NTYPE * NSLOT + t];
        scnt = fmaxf(cs, 1.f);
    }
    __syncthreads();
    if (c >= DIM) return;
    const float inv = 1.f / scnt;

    float sub = 0.f, mul, bia = 0.f;
    if (c < 64) {
        float S = 0.f, Q = 0.f;
#pragma unroll
        for (int k = 0; k < RCHUNK; k++) {
            const float* p = gpart + k * PSTRIDE + t * NSLOT;
            S += p[c]; Q += p[64 + c];
        }
        const float mean = S * inv;
        float var = Q * inv - mean * mean;
        var = fmaxf(var, 0.f);
        mul = rsqrtf(var + EPSV) * weight[t * NFEAT + c];
        sub = mean;
        bia = bias[t * 64 + c];
    } else if (c < 160) {
        const int ch = (c - 64) / 3;
        float N = 0.f;
#pragma unroll
        for (int k = 0; k < RCHUNK; k++)
            N += gpart[k * PSTRIDE + t * NSLOT + 128 + ch];
        mul = rsqrtf(N * inv * (1.f / 3.f) + EPSV) * weight[t * NFEAT + 64 + ch];
    } else {
        const int ch = (c - 160) / 5;
        float N = 0.f;
#pragma unroll
        for (int k = 0; k < RCHUNK; k++)
            N += gpart[k * PSTRIDE + t * NSLOT + 160 + ch];
        mul = rsqrtf(N * inv * 0.2f + EPSV) * weight[t * NFEAT + 96 + ch];
    }
    float* p = params + t * 720;
    p[c] = sub;
    p[240 + c] = mul;
    p[480 + c] = bia;
}

__global__ __launch_bounds__(256) void apply_kernel(const float* __restrict__ x,
        const int* __restrict__ type, const float* __restrict__ params,
        float* __restrict__ out, int B, int nblocks)
{
    // stage all params in LDS: 10 types * 180 float4 (28.8 KB)
    __shared__ float4 sp[NTYPE * 180];
    const int tid = threadIdx.x;
    const float4* __restrict__ pg = (const float4*)params;
    for (int i = tid; i < NTYPE * 180; i += 256) sp[i] = pg[i];
    __syncthreads();

    const int rBase = tid / 60;          // 0..3 active, 4 for tid>=240
    const int c4 = tid - rBase * 60;
    const bool active = tid < 240;
    const float4* __restrict__ xv = (const float4*)x;
    float4* __restrict__ ov = (float4*)out;

    // 8 rows per block per sweep: two independent load chains in flight
    const int rstride = nblocks * 8;
    for (int row0 = blockIdx.x * 8; row0 < B; row0 += rstride) {
        const int r0 = row0 + rBase;
        const int r1 = r0 + 4;
        const bool a0 = active && r0 < B;
        const bool a1 = active && r1 < B;
        int t0 = 0, t1 = 0;
        float4 v0 = {0, 0, 0, 0}, v1 = {0, 0, 0, 0};
        if (a0) { t0 = type[r0]; v0 = xv[(size_t)r0 * 60 + c4]; }
        if (a1) { t1 = type[r1]; v1 = xv[(size_t)r1 * 60 + c4]; }
        if (a0) {
            const float4 s = sp[t0 * 180 + c4];
            const float4 m = sp[t0 * 180 + 60 + c4];
            const float4 b = sp[t0 * 180 + 120 + c4];
            float4 o;
            o.x = (v0.x - s.x) * m.x + b.x;
            o.y = (v0.y - s.y) * m.y + b.y;
            o.z = (v0.z - s.z) * m.z + b.z;
            o.w = (v0.w - s.w) * m.w + b.w;
            ov[(size_t)r0 * 60 + c4] = o;
        }
        if (a1) {
            const float4 s = sp[t1 * 180 + c4];
            const float4 m = sp[t1 * 180 + 60 + c4];
            const float4 b = sp[t1 * 180 + 120 + c4];
            float4 o;
            o.x = (v1.x - s.x) * m.x + b.x;
            o.y = (v1.y - s.y) * m.y + b.y;
            o.z = (v1.z - s.z) * m.z + b.z;
            o.w = (v1.w - s.w) * m.w + b.w;
            ov[(size_t)r1 * 60 + c4] = o;
        }
    }
}

extern "C" void kernel_launch(void* const* d_in, const int* in_sizes, int n_in,
                              void* d_out, int out_size, void* d_ws, size_t ws_size,
                              hipStream_t stream) {
    const float* x      = (const float*)d_in[0];
    const int*   type   = (const int*)d_in[1];
    const float* weight = (const float*)d_in[2];
    const float* bias   = (const float*)d_in[3];
    float* out = (float*)d_out;
    float* ws  = (float*)d_ws;
    const int B = in_sizes[0] / DIM;

    int nblk = 2048;   // 8 blocks/CU * 256 CU: full occupancy for stats
    size_t fixed = (size_t)RCHUNK * PSTRIDE + 7200;
    size_t need_floats = (size_t)nblk * PSTRIDE + fixed;
    if (ws_size < need_floats * 4) {
        nblk = (int)((ws_size / 4 - fixed) / PSTRIDE);
        if (nblk < 1) nblk = 1;
    }
    float* partial = ws;
    float* gpart   = ws + (size_t)nblk * PSTRIDE;
    float* params  = gpart + (size_t)RCHUNK * PSTRIDE;

    hipLaunchKernelGGL(stats_kernel, dim3(nblk), dim3(256), 0, stream,
                       x, type, partial, B, nblk);
    hipLaunchKernelGGL(reduce1_kernel, dim3(7 * RCHUNK), dim3(256), 0, stream,
                       partial, gpart, nblk);
    hipLaunchKernelGGL(finalize_kernel, dim3(NTYPE), dim3(256), 0, stream,
                       gpart, weight, bias, params);
    hipLaunchKernelGGL(apply_kernel, dim3(1280), dim3(256), 0, stream,
                       x, type, params, out, B, 1280);
}

// Round 3
// 379.883 us; speedup vs baseline: 1.2312x; 1.0498x over previous
//
#include <hip/hip_runtime.h>

#define DIM 240
#define NTYPE 10
#define NFEAT 112
#define NSLOT 176      // per-type: 64 sum_x + 64 sum_x2 + 32 vec + 16 tens
#define NRED  1770     // NTYPE*NSLOT + NTYPE counts
#define PSTRIDE 1792   // per-block partial stride in floats (1770 used)
#define RCHUNK 32      // row chunks in reduce1
#define SROWS 16       // rows per stats sweep (outstanding loads per lane)
#define EPSV 1e-5f

typedef float nf4 __attribute__((ext_vector_type(4)));   // native vec for nt-store

// ws layout (floats):
// [0, nblk*PSTRIDE)                          per-block partials
// [P0 = nblk*PSTRIDE, +RCHUNK*PSTRIDE)       chunk partials (reduce1 output)
// [P1 = P0 + RCHUNK*PSTRIDE, +7200)          params: per type t: sub[240], mul[240], bia[240]

__global__ __launch_bounds__(256) void stats_kernel(const float* __restrict__ x,
        const int* __restrict__ type, float* __restrict__ partial, int B, int nblk)
{
    const int tid = threadIdx.x;
    const bool active = tid < DIM;
    const bool isScalar = tid < 64;

    float accA[NTYPE], accB[NTYPE];
#pragma unroll
    for (int t = 0; t < NTYPE; t++) { accA[t] = 0.f; accB[t] = 0.f; }

    // counter contribution: inactive lane 255 adds 1.0 per row into accA[ty]
    const float inactAdd = (tid == 255) ? 1.f : 0.f;

    auto accum = [&](int ty, float v) {
        const float v2 = v * v;
        const float addA = active ? (isScalar ? v : v2) : inactAdd;
#pragma unroll
        for (int t = 0; t < NTYPE; t++) {
            if (t == ty) { accA[t] += addA; accB[t] += v2; }  // ty wave-uniform -> scalar branch
        }
    };

    // SROWS rows per block per sweep: SROWS independent loads in flight per lane
    const int stride = nblk * SROWS;
    for (int row0 = blockIdx.x * SROWS; row0 + (SROWS - 1) < B; row0 += stride) {
        int ty[SROWS];
#pragma unroll
        for (int j = 0; j < SROWS; j++) ty[j] = type[row0 + j];
        float v[SROWS];
#pragma unroll
        for (int j = 0; j < SROWS; j++) v[j] = 0.f;
        if (active) {
            const float* p = x + (size_t)row0 * DIM + tid;
#pragma unroll
            for (int j = 0; j < SROWS; j++) v[j] = p[j * DIM];
        }
#pragma unroll
        for (int j = 0; j < SROWS; j++) accum(ty[j], v[j]);
    }
    // tail rows (B % SROWS != 0) -- handled by block 0 only
    if (blockIdx.x == 0) {
        for (int r = B & ~(SROWS - 1); r < B; r++) {
            const int ty0 = type[r];
            float v = active ? x[(size_t)r * DIM + tid] : 0.f;
            accum(ty0, v);
        }
    }

    // block-level reduction into slot layout, then non-atomic partial flush
    __shared__ float sAcc[NRED];   // 1770
    for (int i = tid; i < NRED; i += 256) sAcc[i] = 0.f;
    __syncthreads();

    if (isScalar) {
#pragma unroll
        for (int t = 0; t < NTYPE; t++) {
            sAcc[t * NSLOT + tid] = accA[t];            // exclusive slot: plain store
            sAcc[t * NSLOT + 64 + tid] = accB[t];
        }
    } else if (tid < 160) {
        const int ch = (tid - 64) / 3;
#pragma unroll
        for (int t = 0; t < NTYPE; t++)
            atomicAdd(&sAcc[t * NSLOT + 128 + ch], accA[t]);   // 3-way LDS atomic
    } else if (tid < DIM) {
        const int ch = (tid - 160) / 5;
#pragma unroll
        for (int t = 0; t < NTYPE; t++)
            atomicAdd(&sAcc[t * NSLOT + 160 + ch], accA[t]);   // 5-way LDS atomic
    } else if (tid == 255) {
#pragma unroll
        for (int t = 0; t < NTYPE; t++)
            sAcc[NTYPE * NSLOT + t] = accA[t];          // counts
    }
    __syncthreads();

    float* __restrict__ dst = partial + (size_t)blockIdx.x * PSTRIDE;
    for (int i = tid; i < NRED; i += 256) dst[i] = sAcc[i];
}

// coalesced cross-block reduction: grid = 7 colChunks x RCHUNK rowChunks
__global__ __launch_bounds__(256) void reduce1_kernel(const float* __restrict__ partial,
        float* __restrict__ gpart, int nblk)
{
    const int colChunk = blockIdx.x % 7;
    const int rowChunk = blockIdx.x / 7;
    const int col = colChunk * 256 + threadIdx.x;       // 0..1791
    const int r0 = (rowChunk * nblk) / RCHUNK;
    const int r1 = ((rowChunk + 1) * nblk) / RCHUNK;
    float acc = 0.f;
#pragma unroll 8
    for (int r = r0; r < r1; r++)
        acc += partial[(size_t)r * PSTRIDE + col];
    gpart[rowChunk * PSTRIDE + col] = acc;
}

__global__ __launch_bounds__(256) void finalize_kernel(const float* __restrict__ gpart,
        const float* __restrict__ weight, const float* __restrict__ bias,
        float* __restrict__ params)
{
    const int t = blockIdx.x;
    const int c = threadIdx.x;

    __shared__ float scnt;
    if (c == 0) {
        float cs = 0.f;
#pragma unroll
        for (int k = 0; k < RCHUNK; k++)
            cs += gpart[k * PSTRIDE + NTYPE * NSLOT + t];
        scnt = fmaxf(cs, 1.f);
    }
    __syncthreads();
    if (c >= DIM) return;
    const float inv = 1.f / scnt;

    float sub = 0.f, mul, bia = 0.f;
    if (c < 64) {
        float S = 0.f, Q = 0.f;
#pragma unroll
        for (int k = 0; k < RCHUNK; k++) {
            const float* p = gpart + k * PSTRIDE + t * NSLOT;
            S += p[c]; Q += p[64 + c];
        }
        const float mean = S * inv;
        float var = Q * inv - mean * mean;
        var = fmaxf(var, 0.f);
        mul = rsqrtf(var + EPSV) * weight[t * NFEAT + c];
        sub = mean;
        bia = bias[t * 64 + c];
    } else if (c < 160) {
        const int ch = (c - 64) / 3;
        float N = 0.f;
#pragma unroll
        for (int k = 0; k < RCHUNK; k++)
            N += gpart[k * PSTRIDE + t * NSLOT + 128 + ch];
        mul = rsqrtf(N * inv * (1.f / 3.f) + EPSV) * weight[t * NFEAT + 64 + ch];
    } else {
        const int ch = (c - 160) / 5;
        float N = 0.f;
#pragma unroll
        for (int k = 0; k < RCHUNK; k++)
            N += gpart[k * PSTRIDE + t * NSLOT + 160 + ch];
        mul = rsqrtf(N * inv * 0.2f + EPSV) * weight[t * NFEAT + 96 + ch];
    }
    float* p = params + t * 720;
    p[c] = sub;
    p[240 + c] = mul;
    p[480 + c] = bia;
}

__global__ __launch_bounds__(256) void apply_kernel(const float* __restrict__ x,
        const int* __restrict__ type, const float* __restrict__ params,
        float* __restrict__ out, int B, int nblocks)
{
    // stage all params in LDS: 10 types * 180 float4 (28.8 KB)
    __shared__ nf4 sp[NTYPE * 180];
    const int tid = threadIdx.x;
    const nf4* __restrict__ pg = (const nf4*)params;
    for (int i = tid; i < NTYPE * 180; i += 256) sp[i] = pg[i];
    __syncthreads();

    const int total = B * 60;                 // total float4 elements
    const nf4* __restrict__ xv = (const nf4*)x;
    nf4* __restrict__ ov = (nf4*)out;
    const int estride = nblocks * 256;

    // grid-stride over float4 elements, all 256 lanes active, 4 chains in flight
    for (int base = blockIdx.x * 256 + tid; base < total; base += estride * 4) {
        int e0 = base, e1 = base + estride, e2 = base + 2 * estride, e3 = base + 3 * estride;
        const bool a0 = e0 < total, a1 = e1 < total, a2 = e2 < total, a3 = e3 < total;
        // exact row = e/60 for all uint32 (magic: ceil(2^37/60), residual 28)
        const int r0 = (int)(((unsigned long long)(unsigned)e0 * 2290649225ull) >> 37);
        const int r1 = a1 ? (int)(((unsigned long long)(unsigned)e1 * 2290649225ull) >> 37) : 0;
        const int r2 = a2 ? (int)(((unsigned long long)(unsigned)e2 * 2290649225ull) >> 37) : 0;
        const int r3 = a3 ? (int)(((unsigned long long)(unsigned)e3 * 2290649225ull) >> 37) : 0;
        const int c0 = e0 - r0 * 60, c1 = e1 - r1 * 60, c2 = e2 - r2 * 60, c3 = e3 - r3 * 60;
        int t0 = 0, t1 = 0, t2 = 0, t3 = 0;
        nf4 v0 = {0,0,0,0}, v1 = {0,0,0,0}, v2 = {0,0,0,0}, v3 = {0,0,0,0};
        if (a0) { t0 = type[r0]; v0 = xv[e0]; }
        if (a1) { t1 = type[r1]; v1 = xv[e1]; }
        if (a2) { t2 = type[r2]; v2 = xv[e2]; }
        if (a3) { t3 = type[r3]; v3 = xv[e3]; }
        if (a0) {
            const nf4 s = sp[t0 * 180 + c0];
            const nf4 m = sp[t0 * 180 + 60 + c0];
            const nf4 b = sp[t0 * 180 + 120 + c0];
            __builtin_nontemporal_store((v0 - s) * m + b, &ov[e0]);
        }
        if (a1) {
            const nf4 s = sp[t1 * 180 + c1];
            const nf4 m = sp[t1 * 180 + 60 + c1];
            const nf4 b = sp[t1 * 180 + 120 + c1];
            __builtin_nontemporal_store((v1 - s) * m + b, &ov[e1]);
        }
        if (a2) {
            const nf4 s = sp[t2 * 180 + c2];
            const nf4 m = sp[t2 * 180 + 60 + c2];
            const nf4 b = sp[t2 * 180 + 120 + c2];
            __builtin_nontemporal_store((v2 - s) * m + b, &ov[e2]);
        }
        if (a3) {
            const nf4 s = sp[t3 * 180 + c3];
            const nf4 m = sp[t3 * 180 + 60 + c3];
            const nf4 b = sp[t3 * 180 + 120 + c3];
            __builtin_nontemporal_store((v3 - s) * m + b, &ov[e3]);
        }
    }
}

extern "C" void kernel_launch(void* const* d_in, const int* in_sizes, int n_in,
                              void* d_out, int out_size, void* d_ws, size_t ws_size,
                              hipStream_t stream) {
    const float* x      = (const float*)d_in[0];
    const int*   type   = (const int*)d_in[1];
    const float* weight = (const float*)d_in[2];
    const float* bias   = (const float*)d_in[3];
    float* out = (float*)d_out;
    float* ws  = (float*)d_ws;
    const int B = in_sizes[0] / DIM;

    int nblk = 2048;   // 8 blocks/CU * 256 CU: full occupancy for stats
    size_t fixed = (size_t)RCHUNK * PSTRIDE + 7200;
    size_t need_floats = (size_t)nblk * PSTRIDE + fixed;
    if (ws_size < need_floats * 4) {
        nblk = (int)((ws_size / 4 - fixed) / PSTRIDE);
        if (nblk < 1) nblk = 1;
    }
    float* partial = ws;
    float* gpart   = ws + (size_t)nblk * PSTRIDE;
    float* params  = gpart + (size_t)RCHUNK * PSTRIDE;

    hipLaunchKernelGGL(stats_kernel, dim3(nblk), dim3(256), 0, stream,
                       x, type, partial, B, nblk);
    hipLaunchKernelGGL(reduce1_kernel, dim3(7 * RCHUNK), dim3(256), 0, stream,
                       partial, gpart, nblk);
    hipLaunchKernelGGL(finalize_kernel, dim3(NTYPE), dim3(256), 0, stream,
                       gpart, weight, bias, params);
    hipLaunchKernelGGL(apply_kernel, dim3(2048), dim3(256), 0, stream,
                       x, type, params, out, B, 2048);
}

// Round 4
// 370.894 us; speedup vs baseline: 1.2610x; 1.0242x over previous
//
#include <hip/hip_runtime.h>

#define DIM 240
#define NTYPE 10
#define NFEAT 112
#define NSLOT 176      // per-type: 64 sum_x + 64 sum_x2 + 32 vec + 16 tens
#define NRED  1770     // NTYPE*NSLOT + NTYPE counts
#define PSTRIDE 1792   // chunk stride in floats (1770 used)
#define RCHUNK 32      // number of global accumulator chunks
#define SROWS 16       // rows per stats sweep (outstanding loads per lane)
#define PT 384         // compact params floats per type: mul[240] sub[64] bia[64] pad[16]
#define EPSV 1e-5f

typedef float nf4 __attribute__((ext_vector_type(4)));   // native vec for nt-store

// ws layout (floats):
// [0, RCHUNK*PSTRIDE)            chunk accumulators (memset to 0, stats atomicAdd)
// [RCHUNK*PSTRIDE, +NTYPE*PT)    compact params

__global__ __launch_bounds__(256) void stats_kernel(const float* __restrict__ x,
        const int* __restrict__ type, float* __restrict__ gpart, int B, int nblk)
{
    const int tid = threadIdx.x;
    const bool active = tid < DIM;
    const bool isScalar = tid < 64;

    float accA[NTYPE], accB[NTYPE];
#pragma unroll
    for (int t = 0; t < NTYPE; t++) { accA[t] = 0.f; accB[t] = 0.f; }

    // counter contribution: inactive lane 255 adds 1.0 per row into accA[ty]
    const float inactAdd = (tid == 255) ? 1.f : 0.f;

    auto accum = [&](int ty, float v) {
        const float v2 = v * v;
        const float addA = active ? (isScalar ? v : v2) : inactAdd;
#pragma unroll
        for (int t = 0; t < NTYPE; t++) {
            if (t == ty) { accA[t] += addA; accB[t] += v2; }  // ty wave-uniform -> scalar branch
        }
    };

    // SROWS rows per block per sweep: SROWS independent loads in flight per lane
    const int stride = nblk * SROWS;
    for (int row0 = blockIdx.x * SROWS; row0 + (SROWS - 1) < B; row0 += stride) {
        int ty[SROWS];
#pragma unroll
        for (int j = 0; j < SROWS; j++) ty[j] = type[row0 + j];
        float v[SROWS];
#pragma unroll
        for (int j = 0; j < SROWS; j++) v[j] = 0.f;
        if (active) {
            const float* p = x + (size_t)row0 * DIM + tid;
#pragma unroll
            for (int j = 0; j < SROWS; j++) v[j] = p[j * DIM];
        }
#pragma unroll
        for (int j = 0; j < SROWS; j++) accum(ty[j], v[j]);
    }
    // tail rows (B % SROWS != 0) -- handled by block 0 only
    if (blockIdx.x == 0) {
        for (int r = B & ~(SROWS - 1); r < B; r++) {
            const int ty0 = type[r];
            float v = active ? x[(size_t)r * DIM + tid] : 0.f;
            accum(ty0, v);
        }
    }

    // block-level reduction into slot layout
    __shared__ float sAcc[NRED];   // 1770
    for (int i = tid; i < NRED; i += 256) sAcc[i] = 0.f;
    __syncthreads();

    if (isScalar) {
#pragma unroll
        for (int t = 0; t < NTYPE; t++) {
            sAcc[t * NSLOT + tid] = accA[t];            // exclusive slot: plain store
            sAcc[t * NSLOT + 64 + tid] = accB[t];
        }
    } else if (tid < 160) {
        const int ch = (tid - 64) / 3;
#pragma unroll
        for (int t = 0; t < NTYPE; t++)
            atomicAdd(&sAcc[t * NSLOT + 128 + ch], accA[t]);   // 3-way LDS atomic
    } else if (tid < DIM) {
        const int ch = (tid - 160) / 5;
#pragma unroll
        for (int t = 0; t < NTYPE; t++)
            atomicAdd(&sAcc[t * NSLOT + 160 + ch], accA[t]);   // 5-way LDS atomic
    } else if (tid == 255) {
#pragma unroll
        for (int t = 0; t < NTYPE; t++)
            sAcc[NTYPE * NSLOT + t] = accA[t];          // counts
    }
    __syncthreads();

    // direct device-scope atomic flush into one of RCHUNK chunk accumulators
    float* __restrict__ dst = gpart + (size_t)(blockIdx.x & (RCHUNK - 1)) * PSTRIDE;
    for (int i = tid; i < NRED; i += 256) atomicAdd(&dst[i], sAcc[i]);
}

__global__ __launch_bounds__(256) void finalize_kernel(const float* __restrict__ gpart,
        const float* __restrict__ weight, const float* __restrict__ bias,
        float* __restrict__ params)
{
    const int t = blockIdx.x;
    const int c = threadIdx.x;

    __shared__ float scnt;
    if (c == 0) {
        float cs = 0.f;
#pragma unroll
        for (int k = 0; k < RCHUNK; k++)
            cs += gpart[k * PSTRIDE + NTYPE * NSLOT + t];
        scnt = fmaxf(cs, 1.f);
    }
    __syncthreads();
    if (c >= DIM) return;
    const float inv = 1.f / scnt;

    float sub = 0.f, mul, bia = 0.f;
    if (c < 64) {
        float S = 0.f, Q = 0.f;
#pragma unroll
        for (int k = 0; k < RCHUNK; k++) {
            const float* p = gpart + k * PSTRIDE + t * NSLOT;
            S += p[c]; Q += p[64 + c];
        }
        const float mean = S * inv;
        float var = Q * inv - mean * mean;
        var = fmaxf(var, 0.f);
        mul = rsqrtf(var + EPSV) * weight[t * NFEAT + c];
        sub = mean;
        bia = bias[t * 64 + c];
    } else if (c < 160) {
        const int ch = (c - 64) / 3;
        float N = 0.f;
#pragma unroll
        for (int k = 0; k < RCHUNK; k++)
            N += gpart[k * PSTRIDE + t * NSLOT + 128 + ch];
        mul = rsqrtf(N * inv * (1.f / 3.f) + EPSV) * weight[t * NFEAT + 64 + ch];
    } else {
        const int ch = (c - 160) / 5;
        float N = 0.f;
#pragma unroll
        for (int k = 0; k < RCHUNK; k++)
            N += gpart[k * PSTRIDE + t * NSLOT + 160 + ch];
        mul = rsqrtf(N * inv * 0.2f + EPSV) * weight[t * NFEAT + 96 + ch];
    }
    // compact layout: mul[0,240) sub[240,304) bia[304,368)
    float* p = params + t * PT;
    p[c] = mul;
    if (c < 64) { p[240 + c] = sub; p[304 + c] = bia; }
}

__global__ __launch_bounds__(256) void apply_kernel(const float* __restrict__ x,
        const int* __restrict__ type, const float* __restrict__ params,
        float* __restrict__ out, int B, int nblocks)
{
    // compact params in LDS: per type 96 float4 = 60 mul4 + 16 sub4 + 16 bia4 + 4 pad
    __shared__ nf4 sp[NTYPE * 96];    // 15.36 KB -> 8 blocks/CU
    const int tid = threadIdx.x;
    const nf4* __restrict__ pg = (const nf4*)params;
    for (int i = tid; i < NTYPE * 96; i += 256) sp[i] = pg[i];
    __syncthreads();

    const int total = B * 60;                 // total float4 elements
    const nf4* __restrict__ xv = (const nf4*)x;
    nf4* __restrict__ ov = (nf4*)out;
    const int estride = nblocks * 256;

    // grid-stride over float4 elements, all 256 lanes active, 4 chains in flight
    for (int base = blockIdx.x * 256 + tid; base < total; base += estride * 4) {
        int e0 = base, e1 = base + estride, e2 = base + 2 * estride, e3 = base + 3 * estride;
        const bool a0 = e0 < total, a1 = e1 < total, a2 = e2 < total, a3 = e3 < total;
        // exact row = e/60 (magic: ceil(2^37/60))
        const int r0 = (int)(((unsigned long long)(unsigned)e0 * 2290649225ull) >> 37);
        const int r1 = a1 ? (int)(((unsigned long long)(unsigned)e1 * 2290649225ull) >> 37) : 0;
        const int r2 = a2 ? (int)(((unsigned long long)(unsigned)e2 * 2290649225ull) >> 37) : 0;
        const int r3 = a3 ? (int)(((unsigned long long)(unsigned)e3 * 2290649225ull) >> 37) : 0;
        const int c0 = e0 - r0 * 60, c1 = e1 - r1 * 60, c2 = e2 - r2 * 60, c3 = e3 - r3 * 60;
        int t0 = 0, t1 = 0, t2 = 0, t3 = 0;
        nf4 v0 = {0,0,0,0}, v1 = {0,0,0,0}, v2 = {0,0,0,0}, v3 = {0,0,0,0};
        if (a0) { t0 = type[r0]; v0 = xv[e0]; }
        if (a1) { t1 = type[r1]; v1 = xv[e1]; }
        if (a2) { t2 = type[r2]; v2 = xv[e2]; }
        if (a3) { t3 = type[r3]; v3 = xv[e3]; }
        if (a0) {
            const nf4 m = sp[t0 * 96 + c0];
            nf4 o = v0 * m;
            if (c0 < 16) o = (v0 - sp[t0 * 96 + 60 + c0]) * m + sp[t0 * 96 + 76 + c0];
            __builtin_nontemporal_store(o, &ov[e0]);
        }
        if (a1) {
            const nf4 m = sp[t1 * 96 + c1];
            nf4 o = v1 * m;
            if (c1 < 16) o = (v1 - sp[t1 * 96 + 60 + c1]) * m + sp[t1 * 96 + 76 + c1];
            __builtin_nontemporal_store(o, &ov[e1]);
        }
        if (a2) {
            const nf4 m = sp[t2 * 96 + c2];
            nf4 o = v2 * m;
            if (c2 < 16) o = (v2 - sp[t2 * 96 + 60 + c2]) * m + sp[t2 * 96 + 76 + c2];
            __builtin_nontemporal_store(o, &ov[e2]);
        }
        if (a3) {
            const nf4 m = sp[t3 * 96 + c3];
            nf4 o = v3 * m;
            if (c3 < 16) o = (v3 - sp[t3 * 96 + 60 + c3]) * m + sp[t3 * 96 + 76 + c3];
            __builtin_nontemporal_store(o, &ov[e3]);
        }
    }
}

extern "C" void kernel_launch(void* const* d_in, const int* in_sizes, int n_in,
                              void* d_out, int out_size, void* d_ws, size_t ws_size,
                              hipStream_t stream) {
    const float* x      = (const float*)d_in[0];
    const int*   type   = (const int*)d_in[1];
    const float* weight = (const float*)d_in[2];
    const float* bias   = (const float*)d_in[3];
    float* out = (float*)d_out;
    float* ws  = (float*)d_ws;
    const int B = in_sizes[0] / DIM;

    float* gpart  = ws;
    float* params = ws + (size_t)RCHUNK * PSTRIDE;

    hipMemsetAsync(gpart, 0, (size_t)RCHUNK * PSTRIDE * sizeof(float), stream);
    hipLaunchKernelGGL(stats_kernel, dim3(2048), dim3(256), 0, stream,
                       x, type, gpart, B, 2048);
    hipLaunchKernelGGL(finalize_kernel, dim3(NTYPE), dim3(256), 0, stream,
                       gpart, weight, bias, params);
    hipLaunchKernelGGL(apply_kernel, dim3(2048), dim3(256), 0, stream,
                       x, type, params, out, B, 2048);
}